// Round 2
// baseline (431.316 us; speedup 1.0000x reference)
//
#include <hip/hip_runtime.h>
#include <hip/hip_bf16.h>

#define VOCAB 50257
#define HID   1024
#define MAXLEN 64

__device__ __forceinline__ float dot4(float4 a, float4 b){
  return a.x*b.x + a.y*b.y + a.z*b.z + a.w*b.w;
}
__device__ __forceinline__ float dot4f(float4 a, const float* v){
  return a.x*v[0] + a.y*v[1] + a.z*v[2] + a.w*v[3];
}

// K1 (fused scores + softmax + attn_applied + combine):
// each block redundantly computes the 64 attn scores (attn_W is 0.5 MB ->
// L2-resident), softmax, and attn_applied into LDS, then 4 waves each do one
// comb_W row: x[r] = relu(dot(row, cat(emb,attn)) + b)
__global__ __launch_bounds__(256) void k_combine_fused(
    const int* tok_p, const float* hidden, const float* enc,
    const float* emb, const float* attn_W, const float* attn_b,
    const float* comb_W, const float* comb_b,
    float* ws_x, float* out_attn){
  int t = threadIdx.x, wave = t>>6, lane = t&63;
  __shared__ float sw[MAXLEN];
  __shared__ float sa[HID];
  int tok = min(max(tok_p[0], 0), VOCAB-1);
  const float4* ef = (const float4*)(emb + (size_t)tok*HID);   // 256 f4
  const float4* hf = (const float4*)hidden;                    // 256 f4
  // scores: wave w computes scores b = w*16 .. w*16+15
  #pragma unroll
  for (int i=0;i<16;i++){
    int b = wave*16 + i;
    const float4* wv = (const float4*)(attn_W + (size_t)b*2048); // 512 f4
    float acc = 0.f;
    #pragma unroll
    for (int c=0;c<4;c++) acc += dot4(wv[c*64+lane],     ef[c*64+lane]);
    #pragma unroll
    for (int c=0;c<4;c++) acc += dot4(wv[256+c*64+lane], hf[c*64+lane]);
    #pragma unroll
    for (int k=32;k>=1;k>>=1) acc += __shfl_xor(acc,k);
    if (lane==0) sw[b] = acc + attn_b[b];
  }
  __syncthreads();
  // softmax over the 64 scores (each wave redundantly; wave 0 stores back)
  float s = sw[lane];
  float m = s;
  #pragma unroll
  for (int k=32;k>=1;k>>=1) m = fmaxf(m, __shfl_xor(m,k));
  float e = expf(s-m), d = e;
  #pragma unroll
  for (int k=32;k>=1;k>>=1) d += __shfl_xor(d,k);
  float w = e/d;
  __syncthreads();           // everyone has read sw before overwrite
  if (wave==0) sw[lane] = w;
  if (blockIdx.x==0 && wave==0) out_attn[lane] = w;
  __syncthreads();
  // attn_applied: thread t owns columns 4t..4t+3 (coalesced float4 rows of enc)
  float4 a4 = make_float4(0.f,0.f,0.f,0.f);
  #pragma unroll 8
  for (int p=0;p<MAXLEN;p++){
    float wp = sw[p];
    float4 ev = *(const float4*)(enc + (size_t)p*HID + t*4);
    a4.x += wp*ev.x; a4.y += wp*ev.y; a4.z += wp*ev.z; a4.w += wp*ev.w;
  }
  *(float4*)(sa + t*4) = a4;
  __syncthreads();
  // one wave per output row
  int row = blockIdx.x*4 + wave;
  const float4* wrow = (const float4*)(comb_W + (size_t)row*2048); // 512 f4
  const float4* av   = (const float4*)sa;                          // 256 f4 (LDS)
  float acc = 0.f;
  #pragma unroll
  for (int c=0;c<4;c++) acc += dot4(wrow[c*64+lane],     ef[c*64+lane]);
  #pragma unroll
  for (int c=0;c<4;c++) acc += dot4(wrow[256+c*64+lane], av[c*64+lane]);
  #pragma unroll
  for (int k=32;k>=1;k>>=1) acc += __shfl_xor(acc,k);
  if (lane==0) ws_x[row] = fmaxf(acc + comb_b[row], 0.f);
}

// K2 (fused GRU matvec + gates): block = 1 hidden unit, 6 waves = 6 row-dots
// (exactly one 4KB row per wave -> 24 waves/CU), then gates (r,z,n) -> h_new.
__global__ __launch_bounds__(384) void k_gru_fused(
    const float* ws_x, const float* hidden,
    const float* Wih, const float* Whh,
    const float* bih, const float* bhh,
    float* ws_h, float* out_h){
  int t = threadIdx.x, wave = t>>6, lane = t&63;
  int hi = blockIdx.x;
  __shared__ float part[6];    // gi_r,gi_z,gi_n,gh_r,gh_z,gh_n
  bool ih = (wave < 3);
  int gg = ih ? wave : wave-3;               // gate 0=r,1=z,2=n
  const float*  W = ih ? Wih : Whh;
  const float*  b = ih ? bih : bhh;
  const float4* vec  = ih ? (const float4*)ws_x : (const float4*)hidden;
  const float4* wrow = (const float4*)(W + ((size_t)gg*HID + hi)*HID); // 256 f4
  float acc = 0.f;
  #pragma unroll
  for (int c=0;c<4;c++) acc += dot4(wrow[c*64+lane], vec[c*64+lane]);
  #pragma unroll
  for (int k=32;k>=1;k>>=1) acc += __shfl_xor(acc,k);
  if (lane==0) part[wave] = acc + b[gg*HID + hi];
  __syncthreads();
  if (t==0){
    float r = 1.f/(1.f+expf(-(part[0] + part[3])));
    float z = 1.f/(1.f+expf(-(part[1] + part[4])));
    float n = tanhf(part[2] + r*part[5]);
    float h = hidden[hi];
    float hn = (1.f-z)*n + z*h;
    ws_h[hi]  = hn;
    out_h[hi] = hn;
  }
}

// K3: logits = out_W @ h_new + out_b, one wave/row, grid-stride over 50257 rows.
// Also per-block online (max, sumexp) stats.
__global__ __launch_bounds__(256) void k_logits(
    const float* wsh, const float* out_W, const float* out_b,
    float* out_logits, float* ws_stats){
  int wave = threadIdx.x>>6, lane = threadIdx.x&63;
  int gw = blockIdx.x*4 + wave;       // 0..8191
  float hv[16];
  #pragma unroll
  for (int c=0;c<4;c++)
    #pragma unroll
    for (int j=0;j<4;j++) hv[c*4+j] = wsh[c*256 + lane*4 + j];
  float m = -INFINITY, s = 0.f;
  for (int row = gw; row < VOCAB; row += 8192) {
    const float4* wrow = (const float4*)(out_W + (size_t)row*HID); // 256 f4
    float acc = 0.f;
    #pragma unroll
    for (int c=0;c<4;c++) acc += dot4f(wrow[c*64+lane], hv + c*4);
    #pragma unroll
    for (int k=32;k>=1;k>>=1) acc += __shfl_xor(acc,k);
    if (lane==0) {
      float logit = acc + out_b[row];
      out_logits[row] = logit;
      if (logit > m) { s = s*expf(m-logit) + 1.f; m = logit; }
      else s += expf(logit-m);
    }
  }
  __shared__ float sm[4], ss[4];
  if (lane==0){ sm[wave]=m; ss[wave]=s; }
  __syncthreads();
  if (threadIdx.x==0) {
    float M = fmaxf(fmaxf(sm[0],sm[1]),fmaxf(sm[2],sm[3]));
    float S = ss[0]*expf(sm[0]-M)+ss[1]*expf(sm[1]-M)
            + ss[2]*expf(sm[2]-M)+ss[3]*expf(sm[3]-M);
    ws_stats[blockIdx.x*2]   = M;
    ws_stats[blockIdx.x*2+1] = S;
  }
}

// K4 (fused lse-reduce + subtract): every block redundantly reduces the
// 2048 (max,sumexp) pairs (16 KB, L2-hot) then subtracts lse from its slice.
__global__ __launch_bounds__(256) void k_logp_fused(
    const float* ws_stats, float* out_logits){
  int t = threadIdx.x;
  float m = -INFINITY, s = 0.f;
  #pragma unroll
  for (int i=t;i<2048;i+=256){
    float mi = ws_stats[2*i], si = ws_stats[2*i+1];
    float M = fmaxf(m,mi);
    s = s*expf(m-M) + si*expf(mi-M);
    m = M;
  }
  #pragma unroll
  for (int k=32;k>=1;k>>=1){
    float mo = __shfl_xor(m,k), so = __shfl_xor(s,k);
    float M = fmaxf(m,mo);
    s = s*expf(m-M) + so*expf(mo-M);
    m = M;
  }
  __shared__ float sm[4], ss[4];
  __shared__ float slse;
  if ((t&63)==0){ sm[t>>6]=m; ss[t>>6]=s; }
  __syncthreads();
  if (t==0){
    float M = fmaxf(fmaxf(sm[0],sm[1]),fmaxf(sm[2],sm[3]));
    float S = ss[0]*expf(sm[0]-M)+ss[1]*expf(sm[1]-M)
            + ss[2]*expf(sm[2]-M)+ss[3]*expf(sm[3]-M);
    slse = M + logf(S);
  }
  __syncthreads();
  int i = blockIdx.x*256 + t;
  if (i < VOCAB) out_logits[i] -= slse;
}

extern "C" void kernel_launch(void* const* d_in, const int* in_sizes, int n_in,
                              void* d_out, int out_size, void* d_ws, size_t ws_size,
                              hipStream_t stream) {
  const int*   tok    = (const int*)d_in[0];
  const float* hidden = (const float*)d_in[1];
  const float* enc    = (const float*)d_in[2];
  const float* emb    = (const float*)d_in[3];
  const float* attn_W = (const float*)d_in[4];
  const float* attn_b = (const float*)d_in[5];
  const float* comb_W = (const float*)d_in[6];
  const float* comb_b = (const float*)d_in[7];
  const float* Wih    = (const float*)d_in[8];
  const float* Whh    = (const float*)d_in[9];
  const float* bih    = (const float*)d_in[10];
  const float* bhh    = (const float*)d_in[11];
  const float* out_W  = (const float*)d_in[12];
  const float* out_b  = (const float*)d_in[13];

  float* out      = (float*)d_out;
  float* out_logp = out;
  float* out_h    = out + VOCAB;
  float* out_attn = out + VOCAB + HID;

  float* ws        = (float*)d_ws;
  float* ws_x      = ws;           // 1024
  float* ws_h      = ws + 1024;    // 1024
  float* ws_stats  = ws + 2048;    // 4096

  k_combine_fused<<<256,  256, 0, stream>>>(tok, hidden, enc, emb, attn_W, attn_b,
                                            comb_W, comb_b, ws_x, out_attn);
  k_gru_fused    <<<1024, 384, 0, stream>>>(ws_x, hidden, Wih, Whh, bih, bhh, ws_h, out_h);
  k_logits       <<<2048, 256, 0, stream>>>(ws_h, out_W, out_b, out_logp, ws_stats);
  k_logp_fused   <<<197,  256, 0, stream>>>(ws_stats, out_logp);
}

// Round 3
// 417.042 us; speedup vs baseline: 1.0342x; 1.0342x over previous
//
#include <hip/hip_runtime.h>
#include <hip/hip_bf16.h>

#define VOCAB 50257
#define HID   1024
#define MAXLEN 64

__device__ __forceinline__ float dot4(float4 a, float4 b){
  return a.x*b.x + a.y*b.y + a.z*b.z + a.w*b.w;
}
__device__ __forceinline__ float dot4f(float4 a, const float* v){
  return a.x*v[0] + a.y*v[1] + a.z*v[2] + a.w*v[3];
}

// K1: attn scores[b] = dot(cat(emb[tok], h), attn_W[b]) + attn_b[b]
__global__ __launch_bounds__(256) void k_attn_scores(
    const int* tok_p, const float* hidden, const float* emb,
    const float* attn_W, const float* attn_b, float* ws_scores){
  int b = blockIdx.x, t = threadIdx.x;
  int tok = min(max(tok_p[0], 0), VOCAB-1);
  const float4* wv = (const float4*)(attn_W + (size_t)b*2048); // 512 x float4
  const float4* ef = (const float4*)(emb + (size_t)tok*HID);   // 256 x float4
  const float4* hf = (const float4*)hidden;                    // 256 x float4
  float acc = dot4(wv[t], ef[t]) + dot4(wv[256+t], hf[t]);
  #pragma unroll
  for (int k=32;k>=1;k>>=1) acc += __shfl_xor(acc,k);
  __shared__ float red[4];
  if ((t&63)==0) red[t>>6] = acc;
  __syncthreads();
  if (t==0) ws_scores[b] = red[0]+red[1]+red[2]+red[3] + attn_b[b];
}

// K2 (fused softmax + attn_applied + combine):
// each block redundantly computes the 64-score softmax (registers) and
// attn_applied (enc L2-resident) into LDS, then 4 waves each do one comb_W
// row: x[r] = relu(dot(row, cat(emb,attn)) + b)
__global__ __launch_bounds__(256) void k_combine_fused(
    const int* tok_p, const float* ws_scores, const float* enc,
    const float* emb, const float* comb_W, const float* comb_b,
    float* ws_x, float* out_attn){
  int t = threadIdx.x, wave = t>>6, lane = t&63;
  __shared__ float sw[MAXLEN];
  __shared__ float sa[HID];
  // softmax over 64 scores (every wave computes redundantly; wave 0 stores)
  float s = ws_scores[lane];
  float m = s;
  #pragma unroll
  for (int k=32;k>=1;k>>=1) m = fmaxf(m, __shfl_xor(m,k));
  float e = expf(s-m), d = e;
  #pragma unroll
  for (int k=32;k>=1;k>>=1) d += __shfl_xor(d,k);
  float w = e/d;
  if (wave==0) sw[lane] = w;
  if (blockIdx.x==0 && wave==0) out_attn[lane] = w;
  __syncthreads();
  // attn_applied: thread t owns columns 4t..4t+3 (coalesced float4 rows of enc)
  float4 a4 = make_float4(0.f,0.f,0.f,0.f);
  #pragma unroll 8
  for (int p=0;p<MAXLEN;p++){
    float wp = sw[p];
    float4 ev = *(const float4*)(enc + (size_t)p*HID + t*4);
    a4.x += wp*ev.x; a4.y += wp*ev.y; a4.z += wp*ev.z; a4.w += wp*ev.w;
  }
  *(float4*)(sa + t*4) = a4;
  __syncthreads();
  // one wave per output row
  int row = blockIdx.x*4 + wave;
  int tok = min(max(tok_p[0], 0), VOCAB-1);
  const float4* wrow = (const float4*)(comb_W + (size_t)row*2048); // 512 f4
  const float4* erow = (const float4*)(emb + (size_t)tok*HID);     // 256 f4
  const float4* av   = (const float4*)sa;                          // 256 f4 (LDS)
  float acc = 0.f;
  #pragma unroll
  for (int c=0;c<4;c++) acc += dot4(wrow[c*64+lane],     erow[c*64+lane]);
  #pragma unroll
  for (int c=0;c<4;c++) acc += dot4(wrow[256+c*64+lane], av[c*64+lane]);
  #pragma unroll
  for (int k=32;k>=1;k>>=1) acc += __shfl_xor(acc,k);
  if (lane==0) ws_x[row] = fmaxf(acc + comb_b[row], 0.f);
}

// K3 (fused GRU matvec + gates): block = 1 hidden unit, 6 waves = 6 row-dots
// (exactly one 4KB row per wave -> 24 waves/CU), then gates (r,z,n) -> h_new.
__global__ __launch_bounds__(384) void k_gru_fused(
    const float* ws_x, const float* hidden,
    const float* Wih, const float* Whh,
    const float* bih, const float* bhh,
    float* ws_h, float* out_h){
  int t = threadIdx.x, wave = t>>6, lane = t&63;
  int hi = blockIdx.x;
  __shared__ float part[6];    // gi_r,gi_z,gi_n,gh_r,gh_z,gh_n
  bool ih = (wave < 3);
  int gg = ih ? wave : wave-3;               // gate 0=r,1=z,2=n
  const float*  W = ih ? Wih : Whh;
  const float*  b = ih ? bih : bhh;
  const float4* vec  = ih ? (const float4*)ws_x : (const float4*)hidden;
  const float4* wrow = (const float4*)(W + ((size_t)gg*HID + hi)*HID); // 256 f4
  float acc = 0.f;
  #pragma unroll
  for (int c=0;c<4;c++) acc += dot4(wrow[c*64+lane], vec[c*64+lane]);
  #pragma unroll
  for (int k=32;k>=1;k>>=1) acc += __shfl_xor(acc,k);
  if (lane==0) part[wave] = acc + b[gg*HID + hi];
  __syncthreads();
  if (t==0){
    float r = 1.f/(1.f+expf(-(part[0] + part[3])));
    float z = 1.f/(1.f+expf(-(part[1] + part[4])));
    float n = tanhf(part[2] + r*part[5]);
    float h = hidden[hi];
    float hn = (1.f-z)*n + z*h;
    ws_h[hi]  = hn;
    out_h[hi] = hn;
  }
}

// K4: logits = out_W @ h_new + out_b, one wave/row, grid-stride over 50257 rows.
// Also per-block online (max, sumexp) stats.
__global__ __launch_bounds__(256) void k_logits(
    const float* wsh, const float* out_W, const float* out_b,
    float* out_logits, float* ws_stats){
  int wave = threadIdx.x>>6, lane = threadIdx.x&63;
  int gw = blockIdx.x*4 + wave;       // 0..8191
  float hv[16];
  #pragma unroll
  for (int c=0;c<4;c++)
    #pragma unroll
    for (int j=0;j<4;j++) hv[c*4+j] = wsh[c*256 + lane*4 + j];
  float m = -INFINITY, s = 0.f;
  for (int row = gw; row < VOCAB; row += 8192) {
    const float4* wrow = (const float4*)(out_W + (size_t)row*HID); // 256 f4
    float acc = 0.f;
    #pragma unroll
    for (int c=0;c<4;c++) acc += dot4f(wrow[c*64+lane], hv + c*4);
    #pragma unroll
    for (int k=32;k>=1;k>>=1) acc += __shfl_xor(acc,k);
    if (lane==0) {
      float logit = acc + out_b[row];
      out_logits[row] = logit;
      if (logit > m) { s = s*expf(m-logit) + 1.f; m = logit; }
      else s += expf(logit-m);
    }
  }
  __shared__ float sm[4], ss[4];
  if (lane==0){ sm[wave]=m; ss[wave]=s; }
  __syncthreads();
  if (threadIdx.x==0) {
    float M = fmaxf(fmaxf(sm[0],sm[1]),fmaxf(sm[2],sm[3]));
    float S = ss[0]*expf(sm[0]-M)+ss[1]*expf(sm[1]-M)
            + ss[2]*expf(sm[2]-M)+ss[3]*expf(sm[3]-M);
    ws_stats[blockIdx.x*2]   = M;
    ws_stats[blockIdx.x*2+1] = S;
  }
}

// K5 (fused lse-reduce + subtract): every block redundantly reduces the
// 2048 (max,sumexp) pairs (16 KB, L2-hot) then subtracts lse from its slice.
__global__ __launch_bounds__(256) void k_logp_fused(
    const float* ws_stats, float* out_logits){
  int t = threadIdx.x;
  float m = -INFINITY, s = 0.f;
  #pragma unroll
  for (int i=t;i<2048;i+=256){
    float mi = ws_stats[2*i], si = ws_stats[2*i+1];
    float M = fmaxf(m,mi);
    s = s*expf(m-M) + si*expf(mi-M);
    m = M;
  }
  #pragma unroll
  for (int k=32;k>=1;k>>=1){
    float mo = __shfl_xor(m,k), so = __shfl_xor(s,k);
    float M = fmaxf(m,mo);
    s = s*expf(m-M) + so*expf(mo-M);
    m = M;
  }
  __shared__ float sm[4], ss[4];
  __shared__ float slse;
  if ((t&63)==0){ sm[t>>6]=m; ss[t>>6]=s; }
  __syncthreads();
  if (t==0){
    float M = fmaxf(fmaxf(sm[0],sm[1]),fmaxf(sm[2],sm[3]));
    float S = ss[0]*expf(sm[0]-M)+ss[1]*expf(sm[1]-M)
            + ss[2]*expf(sm[2]-M)+ss[3]*expf(sm[3]-M);
    slse = M + logf(S);
  }
  __syncthreads();
  int i = blockIdx.x*256 + t;
  if (i < VOCAB) out_logits[i] -= slse;
}

extern "C" void kernel_launch(void* const* d_in, const int* in_sizes, int n_in,
                              void* d_out, int out_size, void* d_ws, size_t ws_size,
                              hipStream_t stream) {
  const int*   tok    = (const int*)d_in[0];
  const float* hidden = (const float*)d_in[1];
  const float* enc    = (const float*)d_in[2];
  const float* emb    = (const float*)d_in[3];
  const float* attn_W = (const float*)d_in[4];
  const float* attn_b = (const float*)d_in[5];
  const float* comb_W = (const float*)d_in[6];
  const float* comb_b = (const float*)d_in[7];
  const float* Wih    = (const float*)d_in[8];
  const float* Whh    = (const float*)d_in[9];
  const float* bih    = (const float*)d_in[10];
  const float* bhh    = (const float*)d_in[11];
  const float* out_W  = (const float*)d_in[12];
  const float* out_b  = (const float*)d_in[13];

  float* out      = (float*)d_out;
  float* out_logp = out;
  float* out_h    = out + VOCAB;
  float* out_attn = out + VOCAB + HID;

  float* ws        = (float*)d_ws;
  float* ws_scores = ws;           // 64 (pad to 128)
  float* ws_x      = ws + 128;     // 1024
  float* ws_h      = ws + 1152;    // 1024
  float* ws_stats  = ws + 2176;    // 4096

  k_attn_scores  <<<64,   256, 0, stream>>>(tok, hidden, emb, attn_W, attn_b, ws_scores);
  k_combine_fused<<<256,  256, 0, stream>>>(tok, ws_scores, enc, emb, comb_W, comb_b, ws_x, out_attn);
  k_gru_fused    <<<1024, 384, 0, stream>>>(ws_x, hidden, Wih, Whh, bih, bhh, ws_h, out_h);
  k_logits       <<<2048, 256, 0, stream>>>(ws_h, out_W, out_b, out_logp, ws_stats);
  k_logp_fused   <<<197,  256, 0, stream>>>(ws_stats, out_logp);
}